// Round 14
// baseline (147.645 us; speedup 1.0000x reference)
//
#include <hip/hip_runtime.h>

// k-means cluster step: N=400000, D=256, K=50 (fp32 in/out).
// Round 14 = round 13 with interval-2 rebalance + ring-2:
//  - WSLOT moved to interval 2 (post-barrier): slot (i+1)&1's readers
//    (A(i-1) iter i-1, B(i-1) iter i int1) are provably done -> RING-2
//    staging (32KB, was 48KB). LDS 67.8KB, still 2 blocks/CU.
//  - ISSUE restructured (lane = 1 row, 8 consecutive f32 via 2 dwordx4) so
//    WSLOT is ONE ds_write_b128/lane (staging writes halved).
//  - ISSUE(i+2) issued after WSLOT(i+1) consumes rA/rB (reg reuse safe);
//    interval-2 vmcnt(0) only ever waits ISSUE(i+1) issued a full iter ago.
//  - scores back to f32 (freed LDS): no dump cvts, exact argmin.
// Phases (validated r10-13): A = X*C^T 32x32 MFMA on waves 14/15;
// argmin waves 8/9; B = onehot^T*X 16x16 MFMA on all 16 waves.

typedef _Float16 f16x8 __attribute__((ext_vector_type(8)));
typedef float    f32x4 __attribute__((ext_vector_type(4)));
typedef float    f32x16 __attribute__((ext_vector_type(16)));
typedef int      i32x4 __attribute__((ext_vector_type(4)));
typedef unsigned int u32x4 __attribute__((ext_vector_type(4)));

constexpr int K = 50, KP = 64, D = 256, KD = K * D;
constexpr int BLK = 1024, GRID = 512, CH = 32;
constexpr int SST = 68;   // f32 score stride: 272B rows, 16B-aligned

#define VMCNT0 asm volatile("s_waitcnt vmcnt(0)" ::: "memory")
#define LGKM0  asm volatile("s_waitcnt lgkmcnt(0)" ::: "memory")
#define SBAR   { __builtin_amdgcn_sched_barrier(0); __builtin_amdgcn_s_barrier(); __builtin_amdgcn_sched_barrier(0); }

__global__ __launch_bounds__(BLK)
void k_fused(const float* __restrict__ x, const float* __restrict__ cc,
             float* __restrict__ partial, float* __restrict__ out,
             int N, int useAtomic) {
    __shared__ _Float16       sC[K * D];        // 25.6 KB, 16B-chunk XOR ^(r&7)
    __shared__ unsigned short sxh[2][CH * D];   // 32 KB f16 ring-2
    __shared__ float          sS[32 * SST];     // 8.7 KB f32 score dump
    __shared__ float          sc2[KP];
    __shared__ int            sidx[2][CH];
    __shared__ int            scnt[K];

    const int tid = threadIdx.x;
    for (int i = tid; i < K * D; i += BLK) sC[i] = (_Float16)0.f;
    if (tid < K) scnt[tid] = 0;
    __syncthreads();
    for (int i = tid; i < KD; i += BLK) {
        int r = i >> 8, col = i & 255, ch = col >> 3, wd = col & 7;
        sC[r * D + (((ch ^ (r & 7)) << 3) | wd)] = (_Float16)cc[i];
    }
    if (tid < KP) {
        float s = 0.f;
        if (tid < K) for (int q = 0; q < D; ++q) { float v = cc[tid * D + q]; s += v * v; }
        sc2[tid] = s;
    }
    __syncthreads();

    const int lane = tid & 63, ci = lane & 15, g = lane >> 4, w = tid >> 6;
    // phase-A role (waves 14,15): one 32x32 tile each (cls 0-31 / 32-63)
    const int wA   = (w >= 14) ? (w - 14) : 0;
    const int ra   = lane & 31;               // point row
    const int dl   = lane >> 5;               // k-subgroup
    const int rakey = (ra & 7) ^ (((ra >> 3) & 1) << 2);
    const int cl32 = wA * 32 + (lane & 31);   // cluster col (0..63)
    const int clkey = (lane & 31) & 7;
    const _Float16* cbp = &sC[(cl32 < K ? cl32 : K - 1) * D];  // clamped row
    // phase-B role (all 16 waves): output n-tile w
    const int bcol = w * 16 + ci, bc3 = bcol >> 3, bce = bcol & 7;

    const int nCh = N / CH;
    const int cpb = nCh / gridDim.x, rem = nCh % gridDim.x;
    const int bid = blockIdx.x;
    const int lo  = bid * cpb + (bid < rem ? bid : rem);
    const int cnt = cpb + (bid < rem ? 1 : 0);

    const float INF = 3.4e38f;
    const float c2A = (cl32 < K) ? sc2[cl32] : INF;

    // staging: wave w owns rows 2w,2w+1; lane = row 2w+(l>>5), cols 8c..8c+7
    // (c = l&31). ISSUE: two dwordx4 (together cover 2 rows fully coalesced).
    // WSLOT: cvt to f16x8, ONE ds_write_b128 at swizzled 16B chunk (c^key).
    const int srow = 2 * w + (lane >> 5);
    const int scol = (lane & 31);
    const int skey = (srow & 7) ^ (((srow >> 3) & 1) << 2);
    f32x4 rA = {0,0,0,0}, rB = {0,0,0,0};
#define ISSUE(t_) { const float* b_ = x + (size_t)(t_) * (CH * D) + srow * D + 8 * scol; \
    rA = *(const f32x4*)(b_); rB = *(const f32x4*)(b_ + 4); }
#define WSLOT(s_) { \
    f16x8 h_ = {(_Float16)rA[0], (_Float16)rA[1], (_Float16)rA[2], (_Float16)rA[3], \
                (_Float16)rB[0], (_Float16)rB[1], (_Float16)rB[2], (_Float16)rB[3]}; \
    *(f16x8*)(&sxh[s_][srow * D + ((scol ^ skey) << 3)]) = h_; }

    f32x4 bacc0 = {0,0,0,0}, bacc1 = {0,0,0,0}, bacc2 = {0,0,0,0}, bacc3 = {0,0,0,0};

    // prologue: slot0 <- chunk lo; issue chunk lo+1
    if (cnt > 0) { ISSUE(lo) VMCNT0; WSLOT(0) if (cnt > 1) ISSUE(lo + 1) }
    LGKM0; SBAR;

    for (int i = 0; i <= cnt; ++i) {
        // ---------------- interval 1: A(i) + B(i-1) ----------------
        if (w >= 14 && i < cnt) {        // phase A: 32x32 MFMA, waves 14/15
            const unsigned short* xb = &sxh[i & 1][0];
            f32x16 acc = {0,0,0,0,0,0,0,0,0,0,0,0,0,0,0,0};
#define A_KS(ks) { \
            const int c_ = (ks) * 2 + dl; \
            f16x8 a = *(const f16x8*)(&xb[ra * D + ((c_ ^ rakey) << 3)]); \
            f16x8 b = *(const f16x8*)(cbp + ((c_ ^ clkey) << 3)); \
            acc = __builtin_amdgcn_mfma_f32_32x32x16_f16(a, b, acc, 0, 0, 0); }
            A_KS(0) A_KS(1) A_KS(2) A_KS(3) A_KS(4) A_KS(5) A_KS(6) A_KS(7)
            A_KS(8) A_KS(9) A_KS(10) A_KS(11) A_KS(12) A_KS(13) A_KS(14) A_KS(15)
#undef A_KS
            // dump f32: row(point) = (r&3)+8*(r>>2)+4*dl, col = cl32
#define DUMP(r) { const int row_ = ((r) & 3) + 8 * ((r) >> 2) + 4 * dl; \
            sS[row_ * SST + cl32] = c2A - 2.f * acc[r]; }
            DUMP(0) DUMP(1) DUMP(2) DUMP(3) DUMP(4) DUMP(5) DUMP(6) DUMP(7)
            DUMP(8) DUMP(9) DUMP(10) DUMP(11) DUMP(12) DUMP(13) DUMP(14) DUMP(15)
#undef DUMP
        }

        if (i >= 1) {                    // phase B: scatter chunk i-1, all waves
            const unsigned short* xbh = &sxh[(i - 1) & 1][0];
            const int jb = (i - 1) & 1;
            i32x4 idA = *(const i32x4*)(&sidx[jb][8 * g]);     // broadcast
            i32x4 idB = *(const i32x4*)(&sidx[jb][8 * g + 4]);
            unsigned short v0, v1, v2, v3, v4, v5, v6, v7;
#define RDH(j) { const int p_ = 8 * g + (j); const int key_ = (j) ^ ((g & 1) << 2); \
            v##j = xbh[p_ * D + ((bc3 ^ key_) << 3) + bce]; }
            RDH(0) RDH(1) RDH(2) RDH(3) RDH(4) RDH(5) RDH(6) RDH(7)
#undef RDH
            unsigned int w0 = (unsigned int)v0 | ((unsigned int)v1 << 16);
            unsigned int w1 = (unsigned int)v2 | ((unsigned int)v3 << 16);
            unsigned int w2 = (unsigned int)v4 | ((unsigned int)v5 << 16);
            unsigned int w3 = (unsigned int)v6 | ((unsigned int)v7 << 16);
            u32x4 W = {w0, w1, w2, w3};
            f16x8 bfr = __builtin_bit_cast(f16x8, W);
#define BMT(M, ACC) { \
            const int cl_ = (M) * 16 + ci; \
            f16x8 a = {(_Float16)(idA[0] == cl_ ? 1.f : 0.f), (_Float16)(idA[1] == cl_ ? 1.f : 0.f), \
                       (_Float16)(idA[2] == cl_ ? 1.f : 0.f), (_Float16)(idA[3] == cl_ ? 1.f : 0.f), \
                       (_Float16)(idB[0] == cl_ ? 1.f : 0.f), (_Float16)(idB[1] == cl_ ? 1.f : 0.f), \
                       (_Float16)(idB[2] == cl_ ? 1.f : 0.f), (_Float16)(idB[3] == cl_ ? 1.f : 0.f)}; \
            ACC = __builtin_amdgcn_mfma_f32_16x16x32_f16(a, bfr, ACC, 0, 0, 0); }
            BMT(0, bacc0) BMT(1, bacc1) BMT(2, bacc2) BMT(3, bacc3)
#undef BMT
        }

        LGKM0; SBAR;   // scores(i) visible; slot (i-1)&1 reads retired

        // ------ interval 2: WSLOT(i+1) -> slot (i+1)&1; ISSUE(i+2); argmin(i)
        if (i + 1 < cnt) {
            VMCNT0;          // waits only ISSUE(i+1), issued a full iter ago
            WSLOT((i + 1) & 1)
            if (i + 2 < cnt) ISSUE(lo + i + 2)
        }

        if (w >= 8 && w < 10 && i < cnt) {   // argmin chunk i, waves 8/9
            const int p_ = (w - 8) * 16 + (lane & 15);
            const int kq = lane >> 4;
            const float* sp = &sS[p_ * SST + kq * 16];
            f32x4 s0 = *(const f32x4*)(sp);
            f32x4 s1 = *(const f32x4*)(sp + 4);
            f32x4 s2 = *(const f32x4*)(sp + 8);
            f32x4 s3 = *(const f32x4*)(sp + 12);
            float bm = s0[0]; int bb = kq * 16;
#define CMP(V, E, OFF) { float s_ = V[E]; int c_ = kq * 16 + (OFF); \
            if (s_ < bm) { bm = s_; bb = c_; } }
            CMP(s0,1,1) CMP(s0,2,2) CMP(s0,3,3)
            CMP(s1,0,4) CMP(s1,1,5) CMP(s1,2,6) CMP(s1,3,7)
            CMP(s2,0,8) CMP(s2,1,9) CMP(s2,2,10) CMP(s2,3,11)
            CMP(s3,0,12) CMP(s3,1,13) CMP(s3,2,14) CMP(s3,3,15)
#undef CMP
            { float pm = __shfl_xor(bm, 16, 64); int pb = __shfl_xor(bb, 16, 64);
              if (pm < bm || (pm == bm && pb < bb)) { bm = pm; bb = pb; } }
            { float pm = __shfl_xor(bm, 32, 64); int pb = __shfl_xor(bb, 32, 64);
              if (pm < bm || (pm == bm && pb < bb)) { bm = pm; bb = pb; } }
            if (kq == 0) { sidx[i & 1][p_] = bb; atomicAdd(&scnt[bb], 1); }
        }
        LGKM0; SBAR;   // slot(i+1) + sidx(i) visible for next iter
    }

    // ---- writeback: D row = M*16+4g+r (cluster), col = bcol ----
    if (useAtomic) {
#define WBK(M, ACC) { \
        { int cl_ = (M)*16 + 4*g + 0; if (cl_ < K) atomicAdd(&out[cl_ * D + bcol], ACC[0]); } \
        { int cl_ = (M)*16 + 4*g + 1; if (cl_ < K) atomicAdd(&out[cl_ * D + bcol], ACC[1]); } \
        { int cl_ = (M)*16 + 4*g + 2; if (cl_ < K) atomicAdd(&out[cl_ * D + bcol], ACC[2]); } \
        { int cl_ = (M)*16 + 4*g + 3; if (cl_ < K) atomicAdd(&out[cl_ * D + bcol], ACC[3]); } }
        WBK(0, bacc0) WBK(1, bacc1) WBK(2, bacc2) WBK(3, bacc3)
#undef WBK
    } else {
        float* pb = partial + (size_t)bid * KD;
#define WBK(M, ACC) { \
        { int cl_ = (M)*16 + 4*g + 0; if (cl_ < K) pb[cl_ * D + bcol] = ACC[0]; } \
        { int cl_ = (M)*16 + 4*g + 1; if (cl_ < K) pb[cl_ * D + bcol] = ACC[1]; } \
        { int cl_ = (M)*16 + 4*g + 2; if (cl_ < K) pb[cl_ * D + bcol] = ACC[2]; } \
        { int cl_ = (M)*16 + 4*g + 3; if (cl_ < K) pb[cl_ * D + bcol] = ACC[3]; } }
        WBK(0, bacc0) WBK(1, bacc1) WBK(2, bacc2) WBK(3, bacc3)
#undef WBK
    }
    __syncthreads();
    for (int k = tid; k < K; k += BLK) atomicAdd(&out[KD + k], (float)scnt[k]);
}

// partial reduction: 8 slices of 64 partials, atomicAdd into zeroed out
__global__ __launch_bounds__(256)
void k_reduce(const float* __restrict__ partial, float* __restrict__ out, int G) {
    const int j  = blockIdx.x * 256 + threadIdx.x;    // < KD
    const int bs = G / 8;
    const int b0 = blockIdx.y * bs;
    float s = 0.f;
    for (int b = b0; b < b0 + bs; ++b) s += partial[(size_t)b * KD + j];
    atomicAdd(&out[j], s);
}

extern "C" void kernel_launch(void* const* d_in, const int* in_sizes, int n_in,
                              void* d_out, int out_size, void* d_ws, size_t ws_size,
                              hipStream_t stream) {
    const float* x = (const float*)d_in[0];
    const float* c = (const float*)d_in[1];
    float* out = (float*)d_out;
    const int N = in_sizes[0] / D;

    float* partial = (float*)d_ws;
    const size_t need = (size_t)GRID * KD * sizeof(float);
    const int useAtomic = (ws_size < need) ? 1 : 0;

    hipMemsetAsync(d_out, 0, (size_t)out_size * sizeof(float), stream);
    k_fused<<<GRID, BLK, 0, stream>>>(x, c, partial, out, N, useAtomic);
    if (!useAtomic) {
        k_reduce<<<dim3(KD / 256, 8), 256, 0, stream>>>(partial, out, GRID);
    }
}

// Round 15
// 136.712 us; speedup vs baseline: 1.0800x; 1.0800x over previous
//
#include <hip/hip_runtime.h>

// k-means cluster step: N=400000, D=256, K=50 (fp32 in/out).
// Round 15 = round 14 + split-A (4 waves, K-halves) + split-argmin (4 waves):
//  interval-1 critical path was A's 16-deep chained MFMA accumulation on 2
//  waves; now 8-deep on 4 waves (12-15). Half-0 dumps c2-2*dotH0, half-1
//  dumps -2*dotH1; argmin (waves 8-11, 8 pts/wave, 8 lanes/pt) sums halves.
//  sS doubles (2 x 8.7KB); LDS 76.5KB -> still 2 blocks/CU. Phase B,
//  staging (ring-2, WSLOT in interval 2), barriers: unchanged from r14.

typedef _Float16 f16x8 __attribute__((ext_vector_type(8)));
typedef float    f32x4 __attribute__((ext_vector_type(4)));
typedef float    f32x16 __attribute__((ext_vector_type(16)));
typedef int      i32x4 __attribute__((ext_vector_type(4)));
typedef unsigned int u32x4 __attribute__((ext_vector_type(4)));

constexpr int K = 50, KP = 64, D = 256, KD = K * D;
constexpr int BLK = 1024, GRID = 512, CH = 32;
constexpr int SST = 68;   // f32 score stride: 272B rows, 16B-aligned

#define VMCNT0 asm volatile("s_waitcnt vmcnt(0)" ::: "memory")
#define LGKM0  asm volatile("s_waitcnt lgkmcnt(0)" ::: "memory")
#define SBAR   { __builtin_amdgcn_sched_barrier(0); __builtin_amdgcn_s_barrier(); __builtin_amdgcn_sched_barrier(0); }

__global__ __launch_bounds__(BLK)
void k_fused(const float* __restrict__ x, const float* __restrict__ cc,
             float* __restrict__ partial, float* __restrict__ out,
             int N, int useAtomic) {
    __shared__ _Float16       sC[K * D];        // 25.6 KB, 16B-chunk XOR ^(r&7)
    __shared__ unsigned short sxh[2][CH * D];   // 32 KB f16 ring-2
    __shared__ float          sS0[32 * SST];    // 8.7 KB scores, K-half 0 (+c2)
    __shared__ float          sS1[32 * SST];    // 8.7 KB scores, K-half 1
    __shared__ float          sc2[KP];
    __shared__ int            sidx[2][CH];
    __shared__ int            scnt[K];

    const int tid = threadIdx.x;
    for (int i = tid; i < K * D; i += BLK) sC[i] = (_Float16)0.f;
    if (tid < K) scnt[tid] = 0;
    __syncthreads();
    for (int i = tid; i < KD; i += BLK) {
        int r = i >> 8, col = i & 255, ch = col >> 3, wd = col & 7;
        sC[r * D + (((ch ^ (r & 7)) << 3) | wd)] = (_Float16)cc[i];
    }
    if (tid < KP) {
        float s = 0.f;
        if (tid < K) for (int q = 0; q < D; ++q) { float v = cc[tid * D + q]; s += v * v; }
        sc2[tid] = s;
    }
    __syncthreads();

    const int lane = tid & 63, ci = lane & 15, g = lane >> 4, w = tid >> 6;
    // phase-A role (waves 12-15): kh = K-half, wA = cluster tile (0/1)
    const int kh   = (w >= 14) ? 1 : 0;
    const int wA   = w & 1;
    const int ra   = lane & 31;               // point row
    const int dl   = lane >> 5;               // k-subgroup
    const int rakey = (ra & 7) ^ (((ra >> 3) & 1) << 2);
    const int cl32 = wA * 32 + (lane & 31);   // cluster col (0..63)
    const int clkey = (lane & 31) & 7;
    const _Float16* cbp = &sC[(cl32 < K ? cl32 : K - 1) * D];  // clamped row
    // phase-B role (all 16 waves): output n-tile w
    const int bcol = w * 16 + ci, bc3 = bcol >> 3, bce = bcol & 7;

    const int nCh = N / CH;
    const int cpb = nCh / gridDim.x, rem = nCh % gridDim.x;
    const int bid = blockIdx.x;
    const int lo  = bid * cpb + (bid < rem ? bid : rem);
    const int cnt = cpb + (bid < rem ? 1 : 0);

    const float INF = 3.4e38f;
    const float c2A = (cl32 < K) ? sc2[cl32] : INF;

    // staging: wave w owns rows 2w,2w+1; lane = row 2w+(l>>5), cols 8c..8c+7
    const int srow = 2 * w + (lane >> 5);
    const int scol = (lane & 31);
    const int skey = (srow & 7) ^ (((srow >> 3) & 1) << 2);
    f32x4 rA = {0,0,0,0}, rB = {0,0,0,0};
#define ISSUE(t_) { const float* b_ = x + (size_t)(t_) * (CH * D) + srow * D + 8 * scol; \
    rA = *(const f32x4*)(b_); rB = *(const f32x4*)(b_ + 4); }
#define WSLOT(s_) { \
    f16x8 h_ = {(_Float16)rA[0], (_Float16)rA[1], (_Float16)rA[2], (_Float16)rA[3], \
                (_Float16)rB[0], (_Float16)rB[1], (_Float16)rB[2], (_Float16)rB[3]}; \
    *(f16x8*)(&sxh[s_][srow * D + ((scol ^ skey) << 3)]) = h_; }

    f32x4 bacc0 = {0,0,0,0}, bacc1 = {0,0,0,0}, bacc2 = {0,0,0,0}, bacc3 = {0,0,0,0};

    // prologue: slot0 <- chunk lo; issue chunk lo+1
    if (cnt > 0) { ISSUE(lo) VMCNT0; WSLOT(0) if (cnt > 1) ISSUE(lo + 1) }
    LGKM0; SBAR;

    for (int i = 0; i <= cnt; ++i) {
        // ---------------- interval 1: A(i) + B(i-1) ----------------
        if (w >= 12 && i < cnt) {        // phase A: 32x32 MFMA, waves 12-15
            const unsigned short* xb = &sxh[i & 1][0];
            f32x16 acc = {0,0,0,0,0,0,0,0,0,0,0,0,0,0,0,0};
#define A_KS(s) { \
            const int c_ = (kh * 8 + (s)) * 2 + dl; \
            f16x8 a = *(const f16x8*)(&xb[ra * D + ((c_ ^ rakey) << 3)]); \
            f16x8 b = *(const f16x8*)(cbp + ((c_ ^ clkey) << 3)); \
            acc = __builtin_amdgcn_mfma_f32_32x32x16_f16(a, b, acc, 0, 0, 0); }
            A_KS(0) A_KS(1) A_KS(2) A_KS(3) A_KS(4) A_KS(5) A_KS(6) A_KS(7)
#undef A_KS
            // dump: row(point) = (r&3)+8*(r>>2)+4*dl, col = cl32
            if (kh == 0) {
#define DUMP(r) { const int row_ = ((r) & 3) + 8 * ((r) >> 2) + 4 * dl; \
                sS0[row_ * SST + cl32] = c2A - 2.f * acc[r]; }
                DUMP(0) DUMP(1) DUMP(2) DUMP(3) DUMP(4) DUMP(5) DUMP(6) DUMP(7)
                DUMP(8) DUMP(9) DUMP(10) DUMP(11) DUMP(12) DUMP(13) DUMP(14) DUMP(15)
#undef DUMP
            } else {
#define DUMP(r) { const int row_ = ((r) & 3) + 8 * ((r) >> 2) + 4 * dl; \
                sS1[row_ * SST + cl32] = -2.f * acc[r]; }
                DUMP(0) DUMP(1) DUMP(2) DUMP(3) DUMP(4) DUMP(5) DUMP(6) DUMP(7)
                DUMP(8) DUMP(9) DUMP(10) DUMP(11) DUMP(12) DUMP(13) DUMP(14) DUMP(15)
#undef DUMP
            }
        }

        if (i >= 1) {                    // phase B: scatter chunk i-1, all waves
            const unsigned short* xbh = &sxh[(i - 1) & 1][0];
            const int jb = (i - 1) & 1;
            i32x4 idA = *(const i32x4*)(&sidx[jb][8 * g]);     // broadcast
            i32x4 idB = *(const i32x4*)(&sidx[jb][8 * g + 4]);
            unsigned short v0, v1, v2, v3, v4, v5, v6, v7;
#define RDH(j) { const int p_ = 8 * g + (j); const int key_ = (j) ^ ((g & 1) << 2); \
            v##j = xbh[p_ * D + ((bc3 ^ key_) << 3) + bce]; }
            RDH(0) RDH(1) RDH(2) RDH(3) RDH(4) RDH(5) RDH(6) RDH(7)
#undef RDH
            unsigned int w0 = (unsigned int)v0 | ((unsigned int)v1 << 16);
            unsigned int w1 = (unsigned int)v2 | ((unsigned int)v3 << 16);
            unsigned int w2 = (unsigned int)v4 | ((unsigned int)v5 << 16);
            unsigned int w3 = (unsigned int)v6 | ((unsigned int)v7 << 16);
            u32x4 W = {w0, w1, w2, w3};
            f16x8 bfr = __builtin_bit_cast(f16x8, W);
#define BMT(M, ACC) { \
            const int cl_ = (M) * 16 + ci; \
            f16x8 a = {(_Float16)(idA[0] == cl_ ? 1.f : 0.f), (_Float16)(idA[1] == cl_ ? 1.f : 0.f), \
                       (_Float16)(idA[2] == cl_ ? 1.f : 0.f), (_Float16)(idA[3] == cl_ ? 1.f : 0.f), \
                       (_Float16)(idB[0] == cl_ ? 1.f : 0.f), (_Float16)(idB[1] == cl_ ? 1.f : 0.f), \
                       (_Float16)(idB[2] == cl_ ? 1.f : 0.f), (_Float16)(idB[3] == cl_ ? 1.f : 0.f)}; \
            ACC = __builtin_amdgcn_mfma_f32_16x16x32_f16(a, bfr, ACC, 0, 0, 0); }
            BMT(0, bacc0) BMT(1, bacc1) BMT(2, bacc2) BMT(3, bacc3)
#undef BMT
        }

        LGKM0; SBAR;   // scores(i) visible; slot (i-1)&1 reads retired

        // ------ interval 2: WSLOT(i+1) -> slot (i+1)&1; ISSUE(i+2); argmin(i)
        if (i + 1 < cnt) {
            VMCNT0;          // waits only ISSUE(i+1), issued a full iter ago
            WSLOT((i + 1) & 1)
            if (i + 2 < cnt) ISSUE(lo + i + 2)
        }

        if (w >= 8 && w < 12 && i < cnt) {   // argmin chunk i, waves 8-11
            const int p_ = (w - 8) * 8 + (lane >> 3);   // point 0..31
            const int q  = lane & 7;                     // col octet
            const float* s0p = &sS0[p_ * SST + 8 * q];
            const float* s1p = &sS1[p_ * SST + 8 * q];
            f32x4 a0 = *(const f32x4*)(s0p), a1 = *(const f32x4*)(s0p + 4);
            f32x4 b0 = *(const f32x4*)(s1p), b1 = *(const f32x4*)(s1p + 4);
            f32x4 u = a0 + b0, v = a1 + b1;
            float bm = u[0]; int bb = 8 * q;
#define CMP(VV, E, OFF) { float s_ = VV[E]; int c_ = 8 * q + (OFF); \
            if (s_ < bm) { bm = s_; bb = c_; } }
            CMP(u,1,1) CMP(u,2,2) CMP(u,3,3)
            CMP(v,0,4) CMP(v,1,5) CMP(v,2,6) CMP(v,3,7)
#undef CMP
            { float pm = __shfl_xor(bm, 1, 64); int pb = __shfl_xor(bb, 1, 64);
              if (pm < bm || (pm == bm && pb < bb)) { bm = pm; bb = pb; } }
            { float pm = __shfl_xor(bm, 2, 64); int pb = __shfl_xor(bb, 2, 64);
              if (pm < bm || (pm == bm && pb < bb)) { bm = pm; bb = pb; } }
            { float pm = __shfl_xor(bm, 4, 64); int pb = __shfl_xor(bb, 4, 64);
              if (pm < bm || (pm == bm && pb < bb)) { bm = pm; bb = pb; } }
            if (q == 0) { sidx[i & 1][p_] = bb; atomicAdd(&scnt[bb], 1); }
        }
        LGKM0; SBAR;   // slot(i+1) + sidx(i) visible for next iter
    }

    // ---- writeback: D row = M*16+4g+r (cluster), col = bcol ----
    if (useAtomic) {
#define WBK(M, ACC) { \
        { int cl_ = (M)*16 + 4*g + 0; if (cl_ < K) atomicAdd(&out[cl_ * D + bcol], ACC[0]); } \
        { int cl_ = (M)*16 + 4*g + 1; if (cl_ < K) atomicAdd(&out[cl_ * D + bcol], ACC[1]); } \
        { int cl_ = (M)*16 + 4*g + 2; if (cl_ < K) atomicAdd(&out[cl_ * D + bcol], ACC[2]); } \
        { int cl_ = (M)*16 + 4*g + 3; if (cl_ < K) atomicAdd(&out[cl_ * D + bcol], ACC[3]); } }
        WBK(0, bacc0) WBK(1, bacc1) WBK(2, bacc2) WBK(3, bacc3)
#undef WBK
    } else {
        float* pb = partial + (size_t)bid * KD;
#define WBK(M, ACC) { \
        { int cl_ = (M)*16 + 4*g + 0; if (cl_ < K) pb[cl_ * D + bcol] = ACC[0]; } \
        { int cl_ = (M)*16 + 4*g + 1; if (cl_ < K) pb[cl_ * D + bcol] = ACC[1]; } \
        { int cl_ = (M)*16 + 4*g + 2; if (cl_ < K) pb[cl_ * D + bcol] = ACC[2]; } \
        { int cl_ = (M)*16 + 4*g + 3; if (cl_ < K) pb[cl_ * D + bcol] = ACC[3]; } }
        WBK(0, bacc0) WBK(1, bacc1) WBK(2, bacc2) WBK(3, bacc3)
#undef WBK
    }
    __syncthreads();
    for (int k = tid; k < K; k += BLK) atomicAdd(&out[KD + k], (float)scnt[k]);
}

// partial reduction: 8 slices of 64 partials, atomicAdd into zeroed out
__global__ __launch_bounds__(256)
void k_reduce(const float* __restrict__ partial, float* __restrict__ out, int G) {
    const int j  = blockIdx.x * 256 + threadIdx.x;    // < KD
    const int bs = G / 8;
    const int b0 = blockIdx.y * bs;
    float s = 0.f;
    for (int b = b0; b < b0 + bs; ++b) s += partial[(size_t)b * KD + j];
    atomicAdd(&out[j], s);
}

extern "C" void kernel_launch(void* const* d_in, const int* in_sizes, int n_in,
                              void* d_out, int out_size, void* d_ws, size_t ws_size,
                              hipStream_t stream) {
    const float* x = (const float*)d_in[0];
    const float* c = (const float*)d_in[1];
    float* out = (float*)d_out;
    const int N = in_sizes[0] / D;

    float* partial = (float*)d_ws;
    const size_t need = (size_t)GRID * KD * sizeof(float);
    const int useAtomic = (ws_size < need) ? 1 : 0;

    hipMemsetAsync(d_out, 0, (size_t)out_size * sizeof(float), stream);
    k_fused<<<GRID, BLK, 0, stream>>>(x, c, partial, out, N, useAtomic);
    if (!useAtomic) {
        k_reduce<<<dim3(KD / 256, 8), 256, 0, stream>>>(partial, out, GRID);
    }
}

// Round 16
// 135.363 us; speedup vs baseline: 1.0907x; 1.0100x over previous
//
#include <hip/hip_runtime.h>

// k-means cluster step: N=400000, D=256, K=50 (fp32 in/out).
// Round 16 = round 15 + P^T-in-LDS phase B (kill the onehot VALU):
//  - argmin waves write a 64x40-stride f16 onehot matrix P^T (ones at
//    [best[p]][p]); waves 0-7 zero the next buffer in interval 2.
//  - phase B A-frag = ONE ds_read_b128 of P^T per m-tile (replaces 32
//    v_cmp + 32 cndmask per lane): layout A[m=lane&15][k=8g+j] == PT[cl][p].
//  - scores dumped as f16 (r13-validated) to fit LDS: 77.5KB, 2 blocks/CU.
//  - phase B before phase A in interval 1 (short chain first).
// Everything else identical to r15 (staging ring-2, split-A K-halves,
// split-argmin, 2 barriers/chunk).

typedef _Float16 f16x8 __attribute__((ext_vector_type(8)));
typedef float    f32x4 __attribute__((ext_vector_type(4)));
typedef float    f32x16 __attribute__((ext_vector_type(16)));
typedef unsigned int u32x4 __attribute__((ext_vector_type(4)));

constexpr int K = 50, KP = 64, D = 256, KD = K * D;
constexpr int BLK = 1024, GRID = 512, CH = 32;
constexpr int SSTH = 72;   // f16 score stride: 144B rows, 16B-aligned
constexpr int PST  = 40;   // P^T f16 stride: 80B = 5x16B (uniform bank quads)

#define VMCNT0 asm volatile("s_waitcnt vmcnt(0)" ::: "memory")
#define LGKM0  asm volatile("s_waitcnt lgkmcnt(0)" ::: "memory")
#define SBAR   { __builtin_amdgcn_sched_barrier(0); __builtin_amdgcn_s_barrier(); __builtin_amdgcn_sched_barrier(0); }

__global__ __launch_bounds__(BLK)
void k_fused(const float* __restrict__ x, const float* __restrict__ cc,
             float* __restrict__ partial, float* __restrict__ out,
             int N, int useAtomic) {
    __shared__ _Float16       sC[K * D];        // 25.6 KB, 16B-chunk XOR ^(r&7)
    __shared__ unsigned short sxh[2][CH * D];   // 32 KB f16 ring-2
    __shared__ alignas(16) _Float16 sS0[32 * SSTH];  // 4.6 KB f16 scores, K-half 0 (+c2)
    __shared__ alignas(16) _Float16 sS1[32 * SSTH];  // 4.6 KB f16 scores, K-half 1
    __shared__ alignas(16) _Float16 sPT[2][64 * PST]; // 10.2 KB onehot^T ping-pong
    __shared__ float          sc2[KP];
    __shared__ int            scnt[K];

    const int tid = threadIdx.x;
    for (int i = tid; i < K * D; i += BLK) sC[i] = (_Float16)0.f;
    for (int i = tid; i < 2 * 64 * PST; i += BLK) sPT[0][i] = (_Float16)0.f;
    if (tid < K) scnt[tid] = 0;
    __syncthreads();
    for (int i = tid; i < KD; i += BLK) {
        int r = i >> 8, col = i & 255, ch = col >> 3, wd = col & 7;
        sC[r * D + (((ch ^ (r & 7)) << 3) | wd)] = (_Float16)cc[i];
    }
    if (tid < KP) {
        float s = 0.f;
        if (tid < K) for (int q = 0; q < D; ++q) { float v = cc[tid * D + q]; s += v * v; }
        sc2[tid] = s;
    }
    __syncthreads();

    const int lane = tid & 63, ci = lane & 15, g = lane >> 4, w = tid >> 6;
    // phase-A role (waves 12-15): kh = K-half, wA = cluster tile (0/1)
    const int kh   = (w >= 14) ? 1 : 0;
    const int wA   = w & 1;
    const int ra   = lane & 31;               // point row
    const int dl   = lane >> 5;               // k-subgroup
    const int rakey = (ra & 7) ^ (((ra >> 3) & 1) << 2);
    const int cl32 = wA * 32 + (lane & 31);   // cluster col (0..63)
    const int clkey = (lane & 31) & 7;
    const _Float16* cbp = &sC[(cl32 < K ? cl32 : K - 1) * D];  // clamped row
    // phase-B role (all 16 waves): output n-tile w
    const int bcol = w * 16 + ci, bc3 = bcol >> 3, bce = bcol & 7;

    const int nCh = N / CH;
    const int cpb = nCh / gridDim.x, rem = nCh % gridDim.x;
    const int bid = blockIdx.x;
    const int lo  = bid * cpb + (bid < rem ? bid : rem);
    const int cnt = cpb + (bid < rem ? 1 : 0);

    const float INF = 3.4e38f;
    const float c2A = (cl32 < K) ? sc2[cl32] : INF;

    // staging: wave w owns rows 2w,2w+1; lane = row 2w+(l>>5), cols 8c..8c+7
    const int srow = 2 * w + (lane >> 5);
    const int scol = (lane & 31);
    const int skey = (srow & 7) ^ (((srow >> 3) & 1) << 2);
    f32x4 rA = {0,0,0,0}, rB = {0,0,0,0};
#define ISSUE(t_) { const float* b_ = x + (size_t)(t_) * (CH * D) + srow * D + 8 * scol; \
    rA = *(const f32x4*)(b_); rB = *(const f32x4*)(b_ + 4); }
#define WSLOT(s_) { \
    f16x8 h_ = {(_Float16)rA[0], (_Float16)rA[1], (_Float16)rA[2], (_Float16)rA[3], \
                (_Float16)rB[0], (_Float16)rB[1], (_Float16)rB[2], (_Float16)rB[3]}; \
    *(f16x8*)(&sxh[s_][srow * D + ((scol ^ skey) << 3)]) = h_; }

    f32x4 bacc0 = {0,0,0,0}, bacc1 = {0,0,0,0}, bacc2 = {0,0,0,0}, bacc3 = {0,0,0,0};

    // prologue: slot0 <- chunk lo; issue chunk lo+1
    if (cnt > 0) { ISSUE(lo) VMCNT0; WSLOT(0) if (cnt > 1) ISSUE(lo + 1) }
    LGKM0; SBAR;

    for (int i = 0; i <= cnt; ++i) {
        // -------- interval 1: B(i-1) first (short chain), then A(i) --------
        if (i >= 1) {                    // phase B: scatter chunk i-1, all waves
            const unsigned short* xbh = &sxh[(i - 1) & 1][0];
            const _Float16* pt = &sPT[(i - 1) & 1][0];
            unsigned short v0, v1, v2, v3, v4, v5, v6, v7;
#define RDH(j) { const int p_ = 8 * g + (j); const int key_ = (j) ^ ((g & 1) << 2); \
            v##j = xbh[p_ * D + ((bc3 ^ key_) << 3) + bce]; }
            RDH(0) RDH(1) RDH(2) RDH(3) RDH(4) RDH(5) RDH(6) RDH(7)
#undef RDH
            unsigned int w0 = (unsigned int)v0 | ((unsigned int)v1 << 16);
            unsigned int w1 = (unsigned int)v2 | ((unsigned int)v3 << 16);
            unsigned int w2 = (unsigned int)v4 | ((unsigned int)v5 << 16);
            unsigned int w3 = (unsigned int)v6 | ((unsigned int)v7 << 16);
            u32x4 W = {w0, w1, w2, w3};
            f16x8 bfr = __builtin_bit_cast(f16x8, W);
#define BMT(M, ACC) { \
            f16x8 a = *(const f16x8*)(pt + ((M) * 16 + ci) * PST + 8 * g); \
            ACC = __builtin_amdgcn_mfma_f32_16x16x32_f16(a, bfr, ACC, 0, 0, 0); }
            BMT(0, bacc0) BMT(1, bacc1) BMT(2, bacc2) BMT(3, bacc3)
#undef BMT
        }

        if (w >= 12 && i < cnt) {        // phase A: 32x32 MFMA, waves 12-15
            const unsigned short* xb = &sxh[i & 1][0];
            f32x16 acc = {0,0,0,0,0,0,0,0,0,0,0,0,0,0,0,0};
#define A_KS(s) { \
            const int c_ = (kh * 8 + (s)) * 2 + dl; \
            f16x8 a = *(const f16x8*)(&xb[ra * D + ((c_ ^ rakey) << 3)]); \
            f16x8 b = *(const f16x8*)(cbp + ((c_ ^ clkey) << 3)); \
            acc = __builtin_amdgcn_mfma_f32_32x32x16_f16(a, b, acc, 0, 0, 0); }
            A_KS(0) A_KS(1) A_KS(2) A_KS(3) A_KS(4) A_KS(5) A_KS(6) A_KS(7)
#undef A_KS
            if (kh == 0) {
#define DUMP(r) { const int row_ = ((r) & 3) + 8 * ((r) >> 2) + 4 * dl; \
                sS0[row_ * SSTH + cl32] = (_Float16)(c2A - 2.f * acc[r]); }
                DUMP(0) DUMP(1) DUMP(2) DUMP(3) DUMP(4) DUMP(5) DUMP(6) DUMP(7)
                DUMP(8) DUMP(9) DUMP(10) DUMP(11) DUMP(12) DUMP(13) DUMP(14) DUMP(15)
#undef DUMP
            } else {
#define DUMP(r) { const int row_ = ((r) & 3) + 8 * ((r) >> 2) + 4 * dl; \
                sS1[row_ * SSTH + cl32] = (_Float16)(-2.f * acc[r]); }
                DUMP(0) DUMP(1) DUMP(2) DUMP(3) DUMP(4) DUMP(5) DUMP(6) DUMP(7)
                DUMP(8) DUMP(9) DUMP(10) DUMP(11) DUMP(12) DUMP(13) DUMP(14) DUMP(15)
#undef DUMP
            }
        }

        LGKM0; SBAR;   // scores(i) visible; slot/PT (i-1)&1 reads retired

        // ---- interval 2: WSLOT(i+1); ISSUE(i+2); zero PT(i+1); argmin(i) ----
        if (i + 1 < cnt) {
            VMCNT0;          // waits only ISSUE(i+1), issued a full iter ago
            WSLOT((i + 1) & 1)
            if (i + 2 < cnt) ISSUE(lo + i + 2)
        }

        if (w < 8 && i + 1 < cnt) {      // zero PT((i+1)&1): 320 b128 writes
            const int z = w * 64 + lane;
            if (z < (64 * PST * 2) / 16) {
                f16x8 zz = {(_Float16)0.f,(_Float16)0.f,(_Float16)0.f,(_Float16)0.f,
                            (_Float16)0.f,(_Float16)0.f,(_Float16)0.f,(_Float16)0.f};
                *(f16x8*)(&sPT[(i + 1) & 1][z * 8]) = zz;
            }
        }

        if (w >= 8 && w < 12 && i < cnt) {   // argmin chunk i, waves 8-11
            const int p_ = (w - 8) * 8 + (lane >> 3);   // point 0..31
            const int q  = lane & 7;                     // col octet
            const _Float16* s0p = &sS0[p_ * SSTH + 8 * q];
            const _Float16* s1p = &sS1[p_ * SSTH + 8 * q];
            f16x8 h0 = *(const f16x8*)(s0p);
            f16x8 h1 = *(const f16x8*)(s1p);
            float bm = (float)h0[0] + (float)h1[0]; int bb = 8 * q;
#define CMP(E) { float s_ = (float)h0[E] + (float)h1[E]; int c_ = 8 * q + (E); \
            if (s_ < bm) { bm = s_; bb = c_; } }
            CMP(1) CMP(2) CMP(3) CMP(4) CMP(5) CMP(6) CMP(7)
#undef CMP
            { float pm = __shfl_xor(bm, 1, 64); int pb = __shfl_xor(bb, 1, 64);
              if (pm < bm || (pm == bm && pb < bb)) { bm = pm; bb = pb; } }
            { float pm = __shfl_xor(bm, 2, 64); int pb = __shfl_xor(bb, 2, 64);
              if (pm < bm || (pm == bm && pb < bb)) { bm = pm; bb = pb; } }
            { float pm = __shfl_xor(bm, 4, 64); int pb = __shfl_xor(bb, 4, 64);
              if (pm < bm || (pm == bm && pb < bb)) { bm = pm; bb = pb; } }
            if (q == 0) {
                sPT[i & 1][bb * PST + p_] = (_Float16)1.f;   // one-write
                atomicAdd(&scnt[bb], 1);
            }
        }
        LGKM0; SBAR;   // slot(i+1), PT zero/ones visible for next iter
    }

    // ---- writeback: D row = M*16+4g+r (cluster), col = bcol ----
    if (useAtomic) {
#define WBK(M, ACC) { \
        { int cl_ = (M)*16 + 4*g + 0; if (cl_ < K) atomicAdd(&out[cl_ * D + bcol], ACC[0]); } \
        { int cl_ = (M)*16 + 4*g + 1; if (cl_ < K) atomicAdd(&out[cl_ * D + bcol], ACC[1]); } \
        { int cl_ = (M)*16 + 4*g + 2; if (cl_ < K) atomicAdd(&out[cl_ * D + bcol], ACC[2]); } \
        { int cl_ = (M)*16 + 4*g + 3; if (cl_ < K) atomicAdd(&out[cl_ * D + bcol], ACC[3]); } }
        WBK(0, bacc0) WBK(1, bacc1) WBK(2, bacc2) WBK(3, bacc3)
#undef WBK
    } else {
        float* pb = partial + (size_t)bid * KD;
#define WBK(M, ACC) { \
        { int cl_ = (M)*16 + 4*g + 0; if (cl_ < K) pb[cl_ * D + bcol] = ACC[0]; } \
        { int cl_ = (M)*16 + 4*g + 1; if (cl_ < K) pb[cl_ * D + bcol] = ACC[1]; } \
        { int cl_ = (M)*16 + 4*g + 2; if (cl_ < K) pb[cl_ * D + bcol] = ACC[2]; } \
        { int cl_ = (M)*16 + 4*g + 3; if (cl_ < K) pb[cl_ * D + bcol] = ACC[3]; } }
        WBK(0, bacc0) WBK(1, bacc1) WBK(2, bacc2) WBK(3, bacc3)
#undef WBK
    }
    __syncthreads();
    for (int k = tid; k < K; k += BLK) atomicAdd(&out[KD + k], (float)scnt[k]);
}

// partial reduction: 8 slices of 64 partials, atomicAdd into zeroed out
__global__ __launch_bounds__(256)
void k_reduce(const float* __restrict__ partial, float* __restrict__ out, int G) {
    const int j  = blockIdx.x * 256 + threadIdx.x;    // < KD
    const int bs = G / 8;
    const int b0 = blockIdx.y * bs;
    float s = 0.f;
    for (int b = b0; b < b0 + bs; ++b) s += partial[(size_t)b * KD + j];
    atomicAdd(&out[j], s);
}

extern "C" void kernel_launch(void* const* d_in, const int* in_sizes, int n_in,
                              void* d_out, int out_size, void* d_ws, size_t ws_size,
                              hipStream_t stream) {
    const float* x = (const float*)d_in[0];
    const float* c = (const float*)d_in[1];
    float* out = (float*)d_out;
    const int N = in_sizes[0] / D;

    float* partial = (float*)d_ws;
    const size_t need = (size_t)GRID * KD * sizeof(float);
    const int useAtomic = (ws_size < need) ? 1 : 0;

    hipMemsetAsync(d_out, 0, (size_t)out_size * sizeof(float), stream);
    k_fused<<<GRID, BLK, 0, stream>>>(x, c, partial, out, N, useAtomic);
    if (!useAtomic) {
        k_reduce<<<dim3(KD / 256, 8), 256, 0, stream>>>(partial, out, GRID);
    }
}

// Round 17
// 133.515 us; speedup vs baseline: 1.1058x; 1.0138x over previous
//
#include <hip/hip_runtime.h>

// k-means cluster step: N=400000, D=256, K=50 (fp32 in/out).
// Round 17 = round 16 DE-PINNED + setprio:
//  - All inline-asm waitcnt/sched_barrier(0)/raw-s_barrier replaced with
//    plain __syncthreads() + register-carried deps (m141 lesson: manual
//    full drains + order-pinning defeat the compiler's fine-grained
//    counted-waitcnt scheduling; rounds adding pinning were neutral/worse).
//  - T5: s_setprio(1) around both MFMA clusters (role-diverse waves ->
//    scheduler can favor MFMA-entering waves; measured +21-39% on phase-
//    split schedules).
// Structure (validated r10-16, unchanged): ring-2 f16 staging; phase A =
// X*C^T 32x32 MFMA on waves 12-15 (K-halves); phase B = PT^T*X 16x16 MFMA
// all 16 waves; argmin waves 8-11; PT onehot in LDS; 2 barriers/chunk.

typedef _Float16 f16x8 __attribute__((ext_vector_type(8)));
typedef float    f32x4 __attribute__((ext_vector_type(4)));
typedef float    f32x16 __attribute__((ext_vector_type(16)));
typedef unsigned int u32x4 __attribute__((ext_vector_type(4)));

constexpr int K = 50, KP = 64, D = 256, KD = K * D;
constexpr int BLK = 1024, GRID = 512, CH = 32;
constexpr int SSTH = 72;   // f16 score stride: 144B rows, 16B-aligned
constexpr int PST  = 40;   // P^T f16 stride: 80B = 5x16B (uniform bank quads)

__global__ __launch_bounds__(BLK)
void k_fused(const float* __restrict__ x, const float* __restrict__ cc,
             float* __restrict__ partial, float* __restrict__ out,
             int N, int useAtomic) {
    __shared__ _Float16       sC[K * D];        // 25.6 KB, 16B-chunk XOR ^(r&7)
    __shared__ unsigned short sxh[2][CH * D];   // 32 KB f16 ring-2
    __shared__ alignas(16) _Float16 sS0[32 * SSTH];  // 4.6 KB f16 scores, half 0 (+c2)
    __shared__ alignas(16) _Float16 sS1[32 * SSTH];  // 4.6 KB f16 scores, half 1
    __shared__ alignas(16) _Float16 sPT[2][64 * PST]; // 10.2 KB onehot^T ping-pong
    __shared__ float          sc2[KP];
    __shared__ int            scnt[K];

    const int tid = threadIdx.x;
    for (int i = tid; i < K * D; i += BLK) sC[i] = (_Float16)0.f;
    for (int i = tid; i < 2 * 64 * PST; i += BLK) sPT[0][i] = (_Float16)0.f;
    if (tid < K) scnt[tid] = 0;
    __syncthreads();
    for (int i = tid; i < KD; i += BLK) {
        int r = i >> 8, col = i & 255, ch = col >> 3, wd = col & 7;
        sC[r * D + (((ch ^ (r & 7)) << 3) | wd)] = (_Float16)cc[i];
    }
    if (tid < KP) {
        float s = 0.f;
        if (tid < K) for (int q = 0; q < D; ++q) { float v = cc[tid * D + q]; s += v * v; }
        sc2[tid] = s;
    }
    __syncthreads();

    const int lane = tid & 63, ci = lane & 15, g = lane >> 4, w = tid >> 6;
    // phase-A role (waves 12-15): kh = K-half, wA = cluster tile (0/1)
    const int kh   = (w >= 14) ? 1 : 0;
    const int wA   = w & 1;
    const int ra   = lane & 31;               // point row
    const int dl   = lane >> 5;               // k-subgroup
    const int rakey = (ra & 7) ^ (((ra >> 3) & 1) << 2);
    const int cl32 = wA * 32 + (lane & 31);   // cluster col (0..63)
    const int clkey = (lane & 31) & 7;
    const _Float16* cbp = &sC[(cl32 < K ? cl32 : K - 1) * D];  // clamped row
    // phase-B role (all 16 waves): output n-tile w
    const int bcol = w * 16 + ci, bc3 = bcol >> 3, bce = bcol & 7;

    const int nCh = N / CH;
    const int cpb = nCh / gridDim.x, rem = nCh % gridDim.x;
    const int bid = blockIdx.x;
    const int lo  = bid * cpb + (bid < rem ? bid : rem);
    const int cnt = cpb + (bid < rem ? 1 : 0);

    const float INF = 3.4e38f;
    const float c2A = (cl32 < K) ? sc2[cl32] : INF;

    // staging: wave w owns rows 2w,2w+1; lane = row 2w+(l>>5), cols 8c..8c+7
    const int srow = 2 * w + (lane >> 5);
    const int scol = (lane & 31);
    const int skey = (srow & 7) ^ (((srow >> 3) & 1) << 2);
    f32x4 rA = {0,0,0,0}, rB = {0,0,0,0};
#define ISSUE(t_) { const float* b_ = x + (size_t)(t_) * (CH * D) + srow * D + 8 * scol; \
    rA = *(const f32x4*)(b_); rB = *(const f32x4*)(b_ + 4); }
#define WSLOT(s_) { \
    f16x8 h_ = {(_Float16)rA[0], (_Float16)rA[1], (_Float16)rA[2], (_Float16)rA[3], \
                (_Float16)rB[0], (_Float16)rB[1], (_Float16)rB[2], (_Float16)rB[3]}; \
    *(f16x8*)(&sxh[s_][srow * D + ((scol ^ skey) << 3)]) = h_; }

    f32x4 bacc0 = {0,0,0,0}, bacc1 = {0,0,0,0}, bacc2 = {0,0,0,0}, bacc3 = {0,0,0,0};

    // prologue: slot0 <- chunk lo (reg-dep wait auto-inserted); issue lo+1
    if (cnt > 0) { ISSUE(lo) WSLOT(0) if (cnt > 1) ISSUE(lo + 1) }
    __syncthreads();

    for (int i = 0; i <= cnt; ++i) {
        // -------- interval 1: B(i-1) first (short chain), then A(i) --------
        if (i >= 1) {                    // phase B: scatter chunk i-1, all waves
            const unsigned short* xbh = &sxh[(i - 1) & 1][0];
            const _Float16* pt = &sPT[(i - 1) & 1][0];
            unsigned short v0, v1, v2, v3, v4, v5, v6, v7;
#define RDH(j) { const int p_ = 8 * g + (j); const int key_ = (j) ^ ((g & 1) << 2); \
            v##j = xbh[p_ * D + ((bc3 ^ key_) << 3) + bce]; }
            RDH(0) RDH(1) RDH(2) RDH(3) RDH(4) RDH(5) RDH(6) RDH(7)
#undef RDH
            unsigned int w0 = (unsigned int)v0 | ((unsigned int)v1 << 16);
            unsigned int w1 = (unsigned int)v2 | ((unsigned int)v3 << 16);
            unsigned int w2 = (unsigned int)v4 | ((unsigned int)v5 << 16);
            unsigned int w3 = (unsigned int)v6 | ((unsigned int)v7 << 16);
            u32x4 W = {w0, w1, w2, w3};
            f16x8 bfr = __builtin_bit_cast(f16x8, W);
            __builtin_amdgcn_s_setprio(1);
#define BMT(M, ACC) { \
            f16x8 a = *(const f16x8*)(pt + ((M) * 16 + ci) * PST + 8 * g); \
            ACC = __builtin_amdgcn_mfma_f32_16x16x32_f16(a, bfr, ACC, 0, 0, 0); }
            BMT(0, bacc0) BMT(1, bacc1) BMT(2, bacc2) BMT(3, bacc3)
#undef BMT
            __builtin_amdgcn_s_setprio(0);
        }

        if (w >= 12 && i < cnt) {        // phase A: 32x32 MFMA, waves 12-15
            const unsigned short* xb = &sxh[i & 1][0];
            f32x16 acc = {0,0,0,0,0,0,0,0,0,0,0,0,0,0,0,0};
            __builtin_amdgcn_s_setprio(1);
#define A_KS(s) { \
            const int c_ = (kh * 8 + (s)) * 2 + dl; \
            f16x8 a = *(const f16x8*)(&xb[ra * D + ((c_ ^ rakey) << 3)]); \
            f16x8 b = *(const f16x8*)(cbp + ((c_ ^ clkey) << 3)); \
            acc = __builtin_amdgcn_mfma_f32_32x32x16_f16(a, b, acc, 0, 0, 0); }
            A_KS(0) A_KS(1) A_KS(2) A_KS(3) A_KS(4) A_KS(5) A_KS(6) A_KS(7)
#undef A_KS
            __builtin_amdgcn_s_setprio(0);
            if (kh == 0) {
#define DUMP(r) { const int row_ = ((r) & 3) + 8 * ((r) >> 2) + 4 * dl; \
                sS0[row_ * SSTH + cl32] = (_Float16)(c2A - 2.f * acc[r]); }
                DUMP(0) DUMP(1) DUMP(2) DUMP(3) DUMP(4) DUMP(5) DUMP(6) DUMP(7)
                DUMP(8) DUMP(9) DUMP(10) DUMP(11) DUMP(12) DUMP(13) DUMP(14) DUMP(15)
#undef DUMP
            } else {
#define DUMP(r) { const int row_ = ((r) & 3) + 8 * ((r) >> 2) + 4 * dl; \
                sS1[row_ * SSTH + cl32] = (_Float16)(-2.f * acc[r]); }
                DUMP(0) DUMP(1) DUMP(2) DUMP(3) DUMP(4) DUMP(5) DUMP(6) DUMP(7)
                DUMP(8) DUMP(9) DUMP(10) DUMP(11) DUMP(12) DUMP(13) DUMP(14) DUMP(15)
#undef DUMP
            }
        }

        __syncthreads();   // scores(i) visible; slot/PT (i-1)&1 reads retired

        // ---- interval 2: WSLOT(i+1); ISSUE(i+2); zero PT(i+1); argmin(i) ----
        if (i + 1 < cnt) {
            WSLOT((i + 1) & 1)            // waits ISSUE(i+1) via reg dep only
            if (i + 2 < cnt) ISSUE(lo + i + 2)
        }

        if (w < 8 && i + 1 < cnt) {      // zero PT((i+1)&1): 320 b128 writes
            const int z = w * 64 + lane;
            if (z < (64 * PST * 2) / 16) {
                f16x8 zz = {(_Float16)0.f,(_Float16)0.f,(_Float16)0.f,(_Float16)0.f,
                            (_Float16)0.f,(_Float16)0.f,(_Float16)0.f,(_Float16)0.f};
                *(f16x8*)(&sPT[(i + 1) & 1][z * 8]) = zz;
            }
        }

        if (w >= 8 && w < 12 && i < cnt) {   // argmin chunk i, waves 8-11
            const int p_ = (w - 8) * 8 + (lane >> 3);   // point 0..31
            const int q  = lane & 7;                     // col octet
            const _Float16* s0p = &sS0[p_ * SSTH + 8 * q];
            const _Float16* s1p = &sS1[p_ * SSTH + 8 * q];
            f16x8 h0 = *(const f16x8*)(s0p);
            f16x8 h1 = *(const f16x8*)(s1p);
            float bm = (float)h0[0] + (float)h1[0]; int bb = 8 * q;
#define CMP(E) { float s_ = (float)h0[E] + (float)h1[E]; int c_ = 8 * q + (E); \
            if (s_ < bm) { bm = s_; bb = c_; } }
            CMP(1) CMP(2) CMP(3) CMP(4) CMP(5) CMP(6) CMP(7)
#undef CMP
            { float pm = __shfl_xor(bm, 1, 64); int pb = __shfl_xor(bb, 1, 64);
              if (pm < bm || (pm == bm && pb < bb)) { bm = pm; bb = pb; } }
            { float pm = __shfl_xor(bm, 2, 64); int pb = __shfl_xor(bb, 2, 64);
              if (pm < bm || (pm == bm && pb < bb)) { bm = pm; bb = pb; } }
            { float pm = __shfl_xor(bm, 4, 64); int pb = __shfl_xor(bb, 4, 64);
              if (pm < bm || (pm == bm && pb < bb)) { bm = pm; bb = pb; } }
            if (q == 0) {
                sPT[i & 1][bb * PST + p_] = (_Float16)1.f;   // one-write
                atomicAdd(&scnt[bb], 1);
            }
        }
        __syncthreads();   // slot(i+1), PT zero/ones visible for next iter
    }

    // ---- writeback: D row = M*16+4g+r (cluster), col = bcol ----
    if (useAtomic) {
#define WBK(M, ACC) { \
        { int cl_ = (M)*16 + 4*g + 0; if (cl_ < K) atomicAdd(&out[cl_ * D + bcol], ACC[0]); } \
        { int cl_ = (M)*16 + 4*g + 1; if (cl_ < K) atomicAdd(&out[cl_ * D + bcol], ACC[1]); } \
        { int cl_ = (M)*16 + 4*g + 2; if (cl_ < K) atomicAdd(&out[cl_ * D + bcol], ACC[2]); } \
        { int cl_ = (M)*16 + 4*g + 3; if (cl_ < K) atomicAdd(&out[cl_ * D + bcol], ACC[3]); } }
        WBK(0, bacc0) WBK(1, bacc1) WBK(2, bacc2) WBK(3, bacc3)
#undef WBK
    } else {
        float* pb = partial + (size_t)bid * KD;
#define WBK(M, ACC) { \
        { int cl_ = (M)*16 + 4*g + 0; if (cl_ < K) pb[cl_ * D + bcol] = ACC[0]; } \
        { int cl_ = (M)*16 + 4*g + 1; if (cl_ < K) pb[cl_ * D + bcol] = ACC[1]; } \
        { int cl_ = (M)*16 + 4*g + 2; if (cl_ < K) pb[cl_ * D + bcol] = ACC[2]; } \
        { int cl_ = (M)*16 + 4*g + 3; if (cl_ < K) pb[cl_ * D + bcol] = ACC[3]; } }
        WBK(0, bacc0) WBK(1, bacc1) WBK(2, bacc2) WBK(3, bacc3)
#undef WBK
    }
    __syncthreads();
    for (int k = tid; k < K; k += BLK) atomicAdd(&out[KD + k], (float)scnt[k]);
}

// partial reduction: 8 slices of 64 partials, atomicAdd into zeroed out
__global__ __launch_bounds__(256)
void k_reduce(const float* __restrict__ partial, float* __restrict__ out, int G) {
    const int j  = blockIdx.x * 256 + threadIdx.x;    // < KD
    const int bs = G / 8;
    const int b0 = blockIdx.y * bs;
    float s = 0.f;
    for (int b = b0; b < b0 + bs; ++b) s += partial[(size_t)b * KD + j];
    atomicAdd(&out[j], s);
}

extern "C" void kernel_launch(void* const* d_in, const int* in_sizes, int n_in,
                              void* d_out, int out_size, void* d_ws, size_t ws_size,
                              hipStream_t stream) {
    const float* x = (const float*)d_in[0];
    const float* c = (const float*)d_in[1];
    float* out = (float*)d_out;
    const int N = in_sizes[0] / D;

    float* partial = (float*)d_ws;
    const size_t need = (size_t)GRID * KD * sizeof(float);
    const int useAtomic = (ws_size < need) ? 1 : 0;

    hipMemsetAsync(d_out, 0, (size_t)out_size * sizeof(float), stream);
    k_fused<<<GRID, BLK, 0, stream>>>(x, c, partial, out, N, useAtomic);
    if (!useAtomic) {
        k_reduce<<<dim3(KD / 256, 8), 256, 0, stream>>>(partial, out, GRID);
    }
}